// Round 1
// 403.528 us; speedup vs baseline: 1.1652x; 1.1652x over previous
//
#include <hip/hip_runtime.h>
#include <math.h>

// Problem constants (setup_inputs): B=8, C=64, N=4096, O=64, K=20
#define Bn 8
#define Cc 64
#define Nn 4096
#define Oo 64
#define Kk 20
#define Kh 10                // half-list size (rank-split pair handlers)
#define QCAP 16              // per-row candidate queue capacity per tile
#define NTOT (Bn*Nn*Kk)      // 655360 elements per BN channel

typedef __attribute__((ext_vector_type(8))) short short8;
typedef __attribute__((ext_vector_type(4))) float f32x4;

__device__ __forceinline__ unsigned bf16_rn(float v) {
  unsigned u = __float_as_uint(v);
  return (u + 0x7FFFu + ((u >> 16) & 1)) >> 16;     // RN-even
}

// ---------------------------------------------------------------- k_split
// x fp32 [b][c][n] -> INTERLEAVED 3-term bf16 split xs3[b][n][{h|m|l}*64+c]
// (192 shorts/row), plus sq[b][n].
//   h = RN(x); m = RN(x-h); l = RN(x-h-m)   (x-h, x-h-m exact in fp32)
__global__ __launch_bounds__(256) void k_split(const float* __restrict__ x,
                                               unsigned short* __restrict__ xs3,
                                               float* __restrict__ sqv) {
  __shared__ float xs[64][68];                  // [c][n], float4-friendly pad
  int tid = threadIdx.x;
  int b = blockIdx.x & 7;
  int n0 = (blockIdx.x >> 3) << 6;
  for (int i = 0; i < 4; i++) {
    int c = i * 16 + (tid >> 4);
    int n = (tid & 15) * 4;
    float4 v = *(const float4*)&x[((size_t)b * Cc + c) * Nn + n0 + n];
    *(float4*)&xs[c][n] = v;
  }
  __syncthreads();
  for (int i = 0; i < 4; i++) {
    int n = i * 16 + (tid >> 4);
    int c = (tid & 15) * 4;
    ushort4 h4, m4, l4;
    unsigned short* hp = (unsigned short*)&h4;
    unsigned short* mp = (unsigned short*)&m4;
    unsigned short* lp = (unsigned short*)&l4;
#pragma unroll
    for (int j = 0; j < 4; j++) {
      float v = xs[c + j][n];
      unsigned hb = bf16_rn(v);
      float hf = __uint_as_float(hb << 16);
      float r1 = v - hf;                                     // exact
      unsigned mb = bf16_rn(r1);
      float mf = __uint_as_float(mb << 16);
      float r2 = r1 - mf;                                    // exact
      unsigned lb = bf16_rn(r2);
      hp[j] = (unsigned short)hb;
      mp[j] = (unsigned short)mb;
      lp[j] = (unsigned short)lb;
    }
    size_t o = ((size_t)(b << 12) + n0 + n) * 192 + c;
    *(ushort4*)&xs3[o] = h4;
    *(ushort4*)&xs3[o + 64] = m4;
    *(ushort4*)&xs3[o + 128] = l4;
  }
  if (tid < 64) {
    float s = 0.f;
#pragma unroll
    for (int c = 0; c < 64; c++) { float v = xs[c][tid]; s = fmaf(v, v, s); }
    sqv[b * Nn + n0 + tid] = s;
  }
}

// ---------------------------------------------------------------- k_y1z
__global__ __launch_bounds__(256) void k_y1z(const float* __restrict__ x,
                                             const float* __restrict__ Wm,
                                             float* __restrict__ y1,
                                             float* __restrict__ z) {
  __shared__ float xs[64][68];                  // [c][n]
  __shared__ float Wl[64][129];
  int tid = threadIdx.x;
  int b = blockIdx.x & 7;
  int n0 = (blockIdx.x >> 3) << 6;
  for (int i = tid; i < 64 * 128; i += 256) Wl[i >> 7][i & 127] = Wm[i];
  for (int i = 0; i < 4; i++) {
    int c = i * 16 + (tid >> 4);
    int n = (tid & 15) * 4;
    float4 v = *(const float4*)&x[((size_t)b * Cc + c) * Nn + n0 + n];
    *(float4*)&xs[c][n] = v;
  }
  __syncthreads();
  int o = tid & 63, ng = tid >> 6;              // ng == wave id -> nb uniform
  for (int p = 0; p < 4; p++) {
    int nb = p * 16 + ng * 4;
    float a1[4] = {0.f, 0.f, 0.f, 0.f};
    float a2[4] = {0.f, 0.f, 0.f, 0.f};
#pragma unroll 8
    for (int c = 0; c < 64; c++) {
      float4 xv = *(const float4*)&xs[c][nb];   // wave-broadcast
      float w1v = Wl[o][c], w2v = Wl[o][64 + c];
      float xa[4] = {xv.x, xv.y, xv.z, xv.w};
#pragma unroll
      for (int j = 0; j < 4; j++) {
        a1[j] = fmaf(xa[j], w1v, a1[j]);
        a2[j] = fmaf(xa[j], w2v, a2[j]);
      }
    }
#pragma unroll
    for (int j = 0; j < 4; j++) {
      size_t off = ((size_t)b * Nn + n0 + nb + j) * 64 + o;
      y1[off] = a1[j];
      z[off] = a2[j] - a1[j];
    }
  }
}

// ---------------------------------------------------------------- k_knn (v12)
// v11 + FULL-TILE ROWS: each wave now owns 16 DISTINCT query rows (the v11
// structure duplicated rows 8-15 of the A-fragment onto rows 0-7 and threw
// away half the MFMA output via the q<2 filter). 64 rows per block, grid
// halves to 512 blocks. Total MFMA count halves; per-wave-tile fixed VALU
// (filter, pend scaffolding, barriers, B ds_reads) halves; drain machinery
// amortizes over 16 rows / 32 handler lanes (16 L,H pairs) per wave.
// Rank-split pair handlers unchanged: even lane (L) holds ranks 0-9, odd
// lane (H) ranks 10-19; per candidate L computes the pass value in O(1),
// one shfl_xor(1), then both lanes run the same 10-deep insert concurrently.
__global__ __launch_bounds__(256, 4) void k_knn(const unsigned short* __restrict__ xs3,
                                                const float* __restrict__ sqv,
                                                int* __restrict__ idxout) {
  __shared__ alignas(16) short Bs[3][64][72];    // [h/m/l][m][c], padded
  __shared__ float thrS[64];
  __shared__ float sqs[64];
  __shared__ alignas(16) float qk[64][20];       // 80B rows, float4-aligned
  __shared__ alignas(16) unsigned short qm[64][24]; // 48B rows, ushort4-aligned
  __shared__ int qcnt[64];

  const int tid = threadIdx.x;
  const int lane = tid & 63;
  const int w = tid >> 6;
  const int b = blockIdx.x & 7;                  // XCD swizzle: batch per XCD
  const int n0 = (blockIdx.x >> 3) << 6;         // 64 row-blocks x 64 rows
  const int lm = lane & 15;                      // candidate col / A row slot
  const int q = lane >> 4;                       // quad: C row = q*4+r
  const bool handler = (lane < 32);
  const int hrow = w * 16 + (lane >> 1);         // row for this handler pair
  const bool isL = (lane & 1) == 0;              // L = ranks 0-9, H = 10-19

  // handler half-list: sorted ascending 10-list in registers
  float hk[Kh];
  int hix[Kh];
#pragma unroll
  for (int kk = 0; kk < Kh; kk++) { hk[kk] = INFINITY; hix[kk] = 0; }

  if (handler && !isL) { thrS[hrow] = INFINITY; qcnt[hrow] = 0; }

  // A fragments: wave w owns 16 DISTINCT rows n0 + w*16 + lm
  const size_t arow = ((size_t)(b << 12) + n0 + w * 16 + lm) * 192;
  short8 ah0 = *(const short8*)&xs3[arow + q * 8];
  short8 ah1 = *(const short8*)&xs3[arow + 32 + q * 8];
  short8 am0 = *(const short8*)&xs3[arow + 64 + q * 8];
  short8 am1 = *(const short8*)&xs3[arow + 96 + q * 8];
  short8 al0 = *(const short8*)&xs3[arow + 128 + q * 8];
  short8 al1 = *(const short8*)&xs3[arow + 160 + q * 8];

  // staging: per-thread source pointer (incremented) + 6 fixed LDS dests
  const unsigned short* gp = xs3 + (size_t)(b << 12) * 192 + tid * 8;
  short* ld[6];
#pragma unroll
  for (int i = 0; i < 6; i++) {
    int f = i * 256 + tid;                       // chunk id in [0,1536)
    int r = f / 24;                              // B row
    int rem = f - r * 24;
    int layer = rem >> 3;
    int qq = rem & 7;
    ld[i] = &Bs[layer][r][qq * 8];
  }

  f32x4 acc[4];

  for (int m0 = 0; m0 < Nn; m0 += 64) {
    __syncthreads();                              // all waves done reading Bs
#pragma unroll
    for (int i = 0; i < 6; i++) {
      short8 v = *(const short8*)(gp + i * 2048);
      *(short8*)ld[i] = v;
    }
    gp += 12288;                                  // next 64 rows
    if (tid < 16) ((float4*)sqs)[tid] = ((const float4*)(sqv + b * Nn + m0))[tid];
    __syncthreads();                              // staging visible

#pragma unroll
    for (int g = 0; g < 4; g++) {
      const int mr = g * 16 + lm;
      short8 bh0 = *(const short8*)&Bs[0][mr][q * 8];
      short8 bh1 = *(const short8*)&Bs[0][mr][32 + q * 8];
      short8 bm0 = *(const short8*)&Bs[1][mr][q * 8];
      short8 bm1 = *(const short8*)&Bs[1][mr][32 + q * 8];
      short8 bl0 = *(const short8*)&Bs[2][mr][q * 8];
      short8 bl1 = *(const short8*)&Bs[2][mr][32 + q * 8];
      f32x4 a = (f32x4){0.f, 0.f, 0.f, 0.f};
      a = __builtin_amdgcn_mfma_f32_16x16x32_bf16(am0, bm0, a, 0, 0, 0);  // mm
      a = __builtin_amdgcn_mfma_f32_16x16x32_bf16(am1, bm1, a, 0, 0, 0);
      a = __builtin_amdgcn_mfma_f32_16x16x32_bf16(ah0, bl0, a, 0, 0, 0);  // hl
      a = __builtin_amdgcn_mfma_f32_16x16x32_bf16(ah1, bl1, a, 0, 0, 0);
      a = __builtin_amdgcn_mfma_f32_16x16x32_bf16(al0, bh0, a, 0, 0, 0);  // lh
      a = __builtin_amdgcn_mfma_f32_16x16x32_bf16(al1, bh1, a, 0, 0, 0);
      a = __builtin_amdgcn_mfma_f32_16x16x32_bf16(ah0, bm0, a, 0, 0, 0);  // hm
      a = __builtin_amdgcn_mfma_f32_16x16x32_bf16(ah1, bm1, a, 0, 0, 0);
      a = __builtin_amdgcn_mfma_f32_16x16x32_bf16(am0, bh0, a, 0, 0, 0);  // mh
      a = __builtin_amdgcn_mfma_f32_16x16x32_bf16(am1, bh1, a, 0, 0, 0);
      a = __builtin_amdgcn_mfma_f32_16x16x32_bf16(ah0, bh0, a, 0, 0, 0);  // hh
      a = __builtin_amdgcn_mfma_f32_16x16x32_bf16(ah1, bh1, a, 0, 0, 0);
      acc[g] = a;
    }

    // keys = sq[m] - 2*dot; ALL 64 lanes hold unique (row=q*4+r, col) now
    unsigned pend = 0;
    {
      float tl[4];
#pragma unroll
      for (int r = 0; r < 4; r++) tl[r] = thrS[w * 16 + q * 4 + r];
#pragma unroll
      for (int g = 0; g < 4; g++) {
        float sv = sqs[g * 16 + lm];
#pragma unroll
        for (int r = 0; r < 4; r++) {
          float key = fmaf(-2.f, acc[g][r], sv);
          acc[g][r] = key;
          if (key < tl[r]) pend |= 1u << (g * 4 + r);
        }
      }
    }

    // wave-private push / drain: NO __syncthreads (DS in-order per wave)
    for (;;) {
      if (pend) {
#pragma unroll
        for (int g = 0; g < 4; g++) {
#pragma unroll
          for (int r = 0; r < 4; r++) {
            unsigned bit = 1u << (g * 4 + r);
            if (pend & bit) {
              int row = w * 16 + q * 4 + r;
              int p = atomicAdd(&qcnt[row], 1);
              if (p < QCAP) {
                qk[row][p] = acc[g][r];
                qm[row][p] = (unsigned short)(m0 + g * 16 + lm);
                pend &= ~bit;
              }
              // else: bit stays set -> retry after drain
            }
          }
        }
      }
      unsigned long long anyovf = __ballot(pend != 0);

      if (handler) {                             // 32 lanes: 16 rows x (L,H)
        int cn = qcnt[hrow];                     // same for both pair lanes
        if (cn > QCAP) cn = QCAP;
        for (int p0 = 0; p0 < cn; p0 += 4) {
          float4 kv4 = *(const float4*)&qk[hrow][p0];      // pair-broadcast
          ushort4 mv4 = *(const ushort4*)&qm[hrow][p0];
          float kva[4] = {kv4.x, kv4.y, kv4.z, kv4.w};
          unsigned short mva[4] = {mv4.x, mv4.y, mv4.z, mv4.w};
#pragma unroll
          for (int j = 0; j < 4; j++) {
            bool valid = (p0 + j < cn);
            float kv = kva[j];
            int ki = (int)mva[j];
            // L decides what flows to H: its evicted max, or kv itself
            bool lins = kv < hk[Kh - 1];
            float pv = lins ? hk[Kh - 1] : kv;
            int pi = lins ? hix[Kh - 1] : ki;
            float rv = __shfl_xor(pv, 1);
            int ri = __shfl_xor(pi, 1);
            float mval = isL ? kv : rv;
            int midx = isL ? ki : ri;
            if (valid && mval < hk[Kh - 1]) {    // both roles: same 10-insert
              bool cm[Kh];
#pragma unroll
              for (int kk = 0; kk < Kh; kk++) cm[kk] = mval < hk[kk];
#pragma unroll
              for (int kk = Kh - 1; kk >= 1; kk--) {
                hk[kk]  = cm[kk] ? (cm[kk - 1] ? hk[kk - 1]  : mval) : hk[kk];
                hix[kk] = cm[kk] ? (cm[kk - 1] ? hix[kk - 1] : midx) : hix[kk];
              }
              if (cm[0]) { hk[0] = mval; hix[0] = midx; }
            }
          }
        }
        if (cn && !isL) { qcnt[hrow] = 0; thrS[hrow] = hk[Kh - 1]; }
      }
      if (!anyovf) break;
      // refilter surviving bits against the tightened thresholds
      if (pend) {
        float tl[4];
#pragma unroll
        for (int r = 0; r < 4; r++) tl[r] = thrS[w * 16 + q * 4 + r];
#pragma unroll
        for (int g = 0; g < 4; g++)
#pragma unroll
          for (int r = 0; r < 4; r++) {
            unsigned bit = 1u << (g * 4 + r);
            if ((pend & bit) && acc[g][r] >= tl[r]) pend &= ~bit;
          }
      }
    }
  }

  // final write: L lane writes ranks 0-9, H lane ranks 10-19
  if (handler) {
    size_t base = ((size_t)b * Nn + n0 + hrow) * Kk + (isL ? 0 : Kh);
#pragma unroll
    for (int kk = 0; kk < Kh; kk++) idxout[base + kk] = hix[kk];
  }
}

// ---------------------------------------------------------------- k_stats
__global__ __launch_bounds__(256) void k_stats(const float* __restrict__ y1,
                                               const float* __restrict__ z,
                                               const int* __restrict__ idxp,
                                               float* __restrict__ parts) {
  __shared__ float rs[4][64];
  __shared__ float rq[4][64];
  int tid = threadIdx.x;
  int o = tid & 63, g = tid >> 6;
  int b = blockIdx.x & 7;                       // XCD swizzle
  int n0 = (blockIdx.x >> 3) << 6;
  const float* y1b = y1 + (size_t)b * Nn * 64;
  float s = 0.f, ss = 0.f;
  for (int t = 0; t < 16; t++) {
    int n = n0 + g + t * 4;
    size_t base = (size_t)b * Nn + n;
    float zv = z[base * 64 + o];
    const int* ip = idxp + base * Kk;
#pragma unroll
    for (int k = 0; k < Kk; k++) {
      int j = ip[k];
      float hv = y1b[(size_t)j * 64 + o] + zv;
      s += hv;
      ss = fmaf(hv, hv, ss);
    }
  }
  rs[g][o] = s;
  rq[g][o] = ss;
  __syncthreads();
  if (tid < 64) {
    parts[(size_t)blockIdx.x * 128 + tid] = rs[0][tid] + rs[1][tid] + rs[2][tid] + rs[3][tid];
    parts[(size_t)blockIdx.x * 128 + 64 + tid] = rq[0][tid] + rq[1][tid] + rq[2][tid] + rq[3][tid];
  }
}

// ---------------------------------------------------------------- k_reduce
__global__ __launch_bounds__(128) void k_reduce(const float* __restrict__ parts,
                                                float* __restrict__ stats) {
  int tid = threadIdx.x;                         // [0,128)
  float s = 0.f;
  for (int i = 0; i < 512; i += 4) {
    s += parts[(size_t)i * 128 + tid] + parts[(size_t)(i + 1) * 128 + tid] +
         parts[(size_t)(i + 2) * 128 + tid] + parts[(size_t)(i + 3) * 128 + tid];
  }
  stats[tid] = s;
}

// ---------------------------------------------------------------- k_out
__global__ __launch_bounds__(256) void k_out(const float* __restrict__ y1,
                                             const float* __restrict__ z,
                                             const int* __restrict__ idxp,
                                             const float* __restrict__ stats,
                                             const float* __restrict__ gamma,
                                             const float* __restrict__ beta,
                                             float* __restrict__ out) {
  __shared__ float T[64][65];
  int tid = threadIdx.x;
  int lane = tid & 63;
  int w = tid >> 6;
  int b = blockIdx.x & 7;                       // XCD swizzle
  int n0 = (blockIdx.x >> 3) << 6;
  int o = lane;
  const float inv = 1.0f / (float)NTOT;
  float mean = stats[o] * inv;
  float var = fmaf(-mean, mean, stats[64 + o] * inv);
  float sc = gamma[o] * rsqrtf(var + 1e-5f);
  float bi = fmaf(-mean, sc, beta[o]);
  const float* y1b = y1 + (size_t)b * Nn * 64;
  for (int t = 0; t < 16; t++) {
    int nl = w + t * 4;
    size_t base = (size_t)b * Nn + n0 + nl;
    float zv = z[base * 64 + o];
    const int* ip = idxp + base * Kk;
    float mv = -INFINITY;
#pragma unroll
    for (int k = 0; k < Kk; k++) {
      int j = ip[k];
      float hv = y1b[(size_t)j * 64 + o] + zv;
      float hn = fmaf(hv, sc, bi);
      float a = (hn >= 0.f) ? hn : 0.2f * hn;
      mv = fmaxf(mv, a);
    }
    T[o][nl] = mv;
  }
  __syncthreads();
  for (int t = 0; t < 16; t++) {
    int oo = w * 16 + t;
    out[((size_t)b * Oo + oo) * Nn + n0 + lane] = T[oo][lane];
  }
}

// ---------------------------------------------------------------- launch
extern "C" void kernel_launch(void* const* d_in, const int* in_sizes, int n_in,
                              void* d_out, int out_size, void* d_ws, size_t ws_size,
                              hipStream_t stream) {
  const float* x = (const float*)d_in[0];
  const float* W = (const float*)d_in[1];
  const float* gamma = (const float*)d_in[2];
  const float* beta = (const float*)d_in[3];
  // d_in[4] is k (=20), baked in as Kk.

  // workspace layout (bytes):
  //   xs3  : [0,       12582912)  bf16 interleaved [b][n][3*64]  (dead after
  //                                k_knn; y1 overlays [0,8M), z [8M,16M))
  //   y1   : [0,        8388608)  B*N*O fp32  (k_y1z, after k_knn)
  //   z    : [8388608, 16777216)  B*N*O fp32  (k_y1z, after k_knn)
  //   sq   : [16777216,16908288)  B*N fp32
  //   stats: [16908288,16908800)  128 fp32
  //   idx20: [16908800,19530240)  B*N*K int32
  //   parts: [19530240,19792384)  512*128 fp32
  char* ws = (char*)d_ws;
  unsigned short* xs3 = (unsigned short*)ws;
  float* y1 = (float*)ws;
  float* z = (float*)(ws + 8388608);
  float* sq = (float*)(ws + 16777216);
  float* stats = (float*)(ws + 16908288);
  int* idx = (int*)(ws + 16908800);
  float* parts = (float*)(ws + 19530240);
  float* out = (float*)d_out;

  k_split<<<Bn * (Nn / 64), 256, 0, stream>>>(x, xs3, sq);
  k_knn<<<Bn * (Nn / 64), 256, 0, stream>>>(xs3, sq, idx);
  k_y1z<<<Bn * (Nn / 64), 256, 0, stream>>>(x, W, y1, z);
  k_stats<<<Bn * (Nn / 64), 256, 0, stream>>>(y1, z, idx, parts);
  k_reduce<<<1, 128, 0, stream>>>(parts, stats);
  k_out<<<Bn * (Nn / 64), 256, 0, stream>>>(y1, z, idx, stats, gamma, beta, out);
}

// Round 2
// 384.295 us; speedup vs baseline: 1.2235x; 1.0500x over previous
//
#include <hip/hip_runtime.h>
#include <math.h>

// Problem constants (setup_inputs): B=8, C=64, N=4096, O=64, K=20
#define Bn 8
#define Cc 64
#define Nn 4096
#define Oo 64
#define Kk 20
#define Kh 10                // half-list size (rank-split pair handlers)
#define QCAP 16              // per-row candidate queue capacity per tile
#define NTOT (Bn*Nn*Kk)      // 655360 elements per BN channel

typedef __attribute__((ext_vector_type(8))) short short8;
typedef __attribute__((ext_vector_type(4))) float f32x4;

__device__ __forceinline__ unsigned bf16_rn(float v) {
  unsigned u = __float_as_uint(v);
  return (u + 0x7FFFu + ((u >> 16) & 1)) >> 16;     // RN-even
}

// ---------------------------------------------------------------- k_split
// x fp32 [b][c][n] -> INTERLEAVED 3-term bf16 split xs3[b][n][{h|m|l}*64+c]
// (192 shorts/row), plus sq[b][n].
//   h = RN(x); m = RN(x-h); l = RN(x-h-m)   (x-h, x-h-m exact in fp32)
__global__ __launch_bounds__(256) void k_split(const float* __restrict__ x,
                                               unsigned short* __restrict__ xs3,
                                               float* __restrict__ sqv) {
  __shared__ float xs[64][68];                  // [c][n], float4-friendly pad
  int tid = threadIdx.x;
  int b = blockIdx.x & 7;
  int n0 = (blockIdx.x >> 3) << 6;
  for (int i = 0; i < 4; i++) {
    int c = i * 16 + (tid >> 4);
    int n = (tid & 15) * 4;
    float4 v = *(const float4*)&x[((size_t)b * Cc + c) * Nn + n0 + n];
    *(float4*)&xs[c][n] = v;
  }
  __syncthreads();
  for (int i = 0; i < 4; i++) {
    int n = i * 16 + (tid >> 4);
    int c = (tid & 15) * 4;
    ushort4 h4, m4, l4;
    unsigned short* hp = (unsigned short*)&h4;
    unsigned short* mp = (unsigned short*)&m4;
    unsigned short* lp = (unsigned short*)&l4;
#pragma unroll
    for (int j = 0; j < 4; j++) {
      float v = xs[c + j][n];
      unsigned hb = bf16_rn(v);
      float hf = __uint_as_float(hb << 16);
      float r1 = v - hf;                                     // exact
      unsigned mb = bf16_rn(r1);
      float mf = __uint_as_float(mb << 16);
      float r2 = r1 - mf;                                    // exact
      unsigned lb = bf16_rn(r2);
      hp[j] = (unsigned short)hb;
      mp[j] = (unsigned short)mb;
      lp[j] = (unsigned short)lb;
    }
    size_t o = ((size_t)(b << 12) + n0 + n) * 192 + c;
    *(ushort4*)&xs3[o] = h4;
    *(ushort4*)&xs3[o + 64] = m4;
    *(ushort4*)&xs3[o + 128] = l4;
  }
  if (tid < 64) {
    float s = 0.f;
#pragma unroll
    for (int c = 0; c < 64; c++) { float v = xs[c][tid]; s = fmaf(v, v, s); }
    sqv[b * Nn + n0 + tid] = s;
  }
}

// ---------------------------------------------------------------- k_y1z
__global__ __launch_bounds__(256) void k_y1z(const float* __restrict__ x,
                                             const float* __restrict__ Wm,
                                             float* __restrict__ y1,
                                             float* __restrict__ z) {
  __shared__ float xs[64][68];                  // [c][n]
  __shared__ float Wl[64][129];
  int tid = threadIdx.x;
  int b = blockIdx.x & 7;
  int n0 = (blockIdx.x >> 3) << 6;
  for (int i = tid; i < 64 * 128; i += 256) Wl[i >> 7][i & 127] = Wm[i];
  for (int i = 0; i < 4; i++) {
    int c = i * 16 + (tid >> 4);
    int n = (tid & 15) * 4;
    float4 v = *(const float4*)&x[((size_t)b * Cc + c) * Nn + n0 + n];
    *(float4*)&xs[c][n] = v;
  }
  __syncthreads();
  int o = tid & 63, ng = tid >> 6;              // ng == wave id -> nb uniform
  for (int p = 0; p < 4; p++) {
    int nb = p * 16 + ng * 4;
    float a1[4] = {0.f, 0.f, 0.f, 0.f};
    float a2[4] = {0.f, 0.f, 0.f, 0.f};
#pragma unroll 8
    for (int c = 0; c < 64; c++) {
      float4 xv = *(const float4*)&xs[c][nb];   // wave-broadcast
      float w1v = Wl[o][c], w2v = Wl[o][64 + c];
      float xa[4] = {xv.x, xv.y, xv.z, xv.w};
#pragma unroll
      for (int j = 0; j < 4; j++) {
        a1[j] = fmaf(xa[j], w1v, a1[j]);
        a2[j] = fmaf(xa[j], w2v, a2[j]);
      }
    }
#pragma unroll
    for (int j = 0; j < 4; j++) {
      size_t off = ((size_t)b * Nn + n0 + nb + j) * 64 + o;
      y1[off] = a1[j];
      z[off] = a2[j] - a1[j];
    }
  }
}

// ---------------------------------------------------------------- k_knn (v13)
// v12 + M-RANGE SPLIT FOR OCCUPANCY: v12's 512-block grid gave only 2 waves
// per SIMD (Occupancy 22%), leaving MfmaUtil+VALUBusy at 50% combined issue
// (latency-bound). Now 8 waves (512 thr): waves 0-3 (group 0) scan
// m in [0,2048), waves 4-7 (group 1) scan [2048,4096), same 64 rows, each
// group with its own B-stage buffer / queues / thresholds (LDS 36.9->73.2KB,
// still 2 blocks/CU -> 16 waves/CU = 4 waves/SIMD). Total MFMA/VALU work
// unchanged; per-wave tile count halves; cross-wave overlap hides the
// stage+drain latency. End merge: group 1 publishes its rank-sorted 20-list
// via LDS, group 0's pair-handlers run them through the normal insert
// machinery (20 inserts/row). Tie semantics preserved: group-0 indices all
// < group-1 indices, insertion strict '<' -> equal keys resolve to lower
// index exactly as a sequential ascending scan.
__global__ __launch_bounds__(512, 4) void k_knn(const unsigned short* __restrict__ xs3,
                                                const float* __restrict__ sqv,
                                                int* __restrict__ idxout) {
  __shared__ alignas(16) short Bs[2][3][64][72]; // [grp][h/m/l][m][c], padded
  __shared__ float thrS[2][64];
  __shared__ float sqs[2][64];
  __shared__ alignas(16) float qk[2][64][20];    // 80B rows, float4-aligned
  __shared__ alignas(16) unsigned short qm[2][64][24]; // 48B rows, ushort4-aligned
  __shared__ int qcnt[2][64];

  const int tid = threadIdx.x;
  const int lane = tid & 63;
  const int w = tid >> 6;                        // 0..7
  const int grp = w >> 2;                        // m-range group
  const int wg = w & 3;                          // wave within group
  const int tig = tid & 255;                     // thread within group
  const int b = blockIdx.x & 7;                  // XCD swizzle: batch per XCD
  const int n0 = (blockIdx.x >> 3) << 6;         // 64 row-blocks x 64 rows
  const int lm = lane & 15;                      // candidate col / A row slot
  const int q = lane >> 4;                       // quad: C row = q*4+r
  const bool handler = (lane < 32);
  const int hrow = wg * 16 + (lane >> 1);        // row for this handler pair
  const bool isL = (lane & 1) == 0;              // L = ranks 0-9, H = 10-19

  // handler half-list: sorted ascending 10-list in registers
  float hk[Kh];
  int hix[Kh];
#pragma unroll
  for (int kk = 0; kk < Kh; kk++) { hk[kk] = INFINITY; hix[kk] = 0; }

  if (handler && !isL) { thrS[grp][hrow] = INFINITY; qcnt[grp][hrow] = 0; }

  // A fragments: wave owns 16 DISTINCT rows n0 + wg*16 + lm (one wave per
  // group covers each row-set; the two waves scan disjoint m-halves)
  const size_t arow = ((size_t)(b << 12) + n0 + wg * 16 + lm) * 192;
  short8 ah0 = *(const short8*)&xs3[arow + q * 8];
  short8 ah1 = *(const short8*)&xs3[arow + 32 + q * 8];
  short8 am0 = *(const short8*)&xs3[arow + 64 + q * 8];
  short8 am1 = *(const short8*)&xs3[arow + 96 + q * 8];
  short8 al0 = *(const short8*)&xs3[arow + 128 + q * 8];
  short8 al1 = *(const short8*)&xs3[arow + 160 + q * 8];

  // staging: per-thread source pointer (incremented) + 6 fixed LDS dests
  const unsigned short* gp = xs3 + ((size_t)(b << 12) + grp * 2048) * 192 + tig * 8;
  short* ld[6];
#pragma unroll
  for (int i = 0; i < 6; i++) {
    int f = i * 256 + tig;                       // chunk id in [0,1536)
    int r = f / 24;                              // B row
    int rem = f - r * 24;
    int layer = rem >> 3;
    int qq = rem & 7;
    ld[i] = &Bs[grp][layer][r][qq * 8];
  }

  f32x4 acc[4];

  for (int t = 0; t < 32; t++) {
    const int m0 = grp * 2048 + t * 64;
    __syncthreads();                              // all waves done reading Bs
#pragma unroll
    for (int i = 0; i < 6; i++) {
      short8 v = *(const short8*)(gp + i * 2048);
      *(short8*)ld[i] = v;
    }
    gp += 12288;                                  // next 64 rows
    if (tig < 16) ((float4*)sqs[grp])[tig] = ((const float4*)(sqv + b * Nn + m0))[tig];
    __syncthreads();                              // staging visible

#pragma unroll
    for (int g = 0; g < 4; g++) {
      const int mr = g * 16 + lm;
      short8 bh0 = *(const short8*)&Bs[grp][0][mr][q * 8];
      short8 bh1 = *(const short8*)&Bs[grp][0][mr][32 + q * 8];
      short8 bm0 = *(const short8*)&Bs[grp][1][mr][q * 8];
      short8 bm1 = *(const short8*)&Bs[grp][1][mr][32 + q * 8];
      short8 bl0 = *(const short8*)&Bs[grp][2][mr][q * 8];
      short8 bl1 = *(const short8*)&Bs[grp][2][mr][32 + q * 8];
      f32x4 a = (f32x4){0.f, 0.f, 0.f, 0.f};
      a = __builtin_amdgcn_mfma_f32_16x16x32_bf16(am0, bm0, a, 0, 0, 0);  // mm
      a = __builtin_amdgcn_mfma_f32_16x16x32_bf16(am1, bm1, a, 0, 0, 0);
      a = __builtin_amdgcn_mfma_f32_16x16x32_bf16(ah0, bl0, a, 0, 0, 0);  // hl
      a = __builtin_amdgcn_mfma_f32_16x16x32_bf16(ah1, bl1, a, 0, 0, 0);
      a = __builtin_amdgcn_mfma_f32_16x16x32_bf16(al0, bh0, a, 0, 0, 0);  // lh
      a = __builtin_amdgcn_mfma_f32_16x16x32_bf16(al1, bh1, a, 0, 0, 0);
      a = __builtin_amdgcn_mfma_f32_16x16x32_bf16(ah0, bm0, a, 0, 0, 0);  // hm
      a = __builtin_amdgcn_mfma_f32_16x16x32_bf16(ah1, bm1, a, 0, 0, 0);
      a = __builtin_amdgcn_mfma_f32_16x16x32_bf16(am0, bh0, a, 0, 0, 0);  // mh
      a = __builtin_amdgcn_mfma_f32_16x16x32_bf16(am1, bh1, a, 0, 0, 0);
      a = __builtin_amdgcn_mfma_f32_16x16x32_bf16(ah0, bh0, a, 0, 0, 0);  // hh
      a = __builtin_amdgcn_mfma_f32_16x16x32_bf16(ah1, bh1, a, 0, 0, 0);
      acc[g] = a;
    }

    // keys = sq[m] - 2*dot; all 64 lanes hold unique (row=q*4+r, col)
    unsigned pend = 0;
    {
      float tl[4];
#pragma unroll
      for (int r = 0; r < 4; r++) tl[r] = thrS[grp][wg * 16 + q * 4 + r];
#pragma unroll
      for (int g = 0; g < 4; g++) {
        float sv = sqs[grp][g * 16 + lm];
#pragma unroll
        for (int r = 0; r < 4; r++) {
          float key = fmaf(-2.f, acc[g][r], sv);
          acc[g][r] = key;
          if (key < tl[r]) pend |= 1u << (g * 4 + r);
        }
      }
    }

    // wave-private push / drain: NO __syncthreads (DS in-order per wave;
    // each wave pushes/drains only its own 16 rows within its group)
    for (;;) {
      if (pend) {
#pragma unroll
        for (int g = 0; g < 4; g++) {
#pragma unroll
          for (int r = 0; r < 4; r++) {
            unsigned bit = 1u << (g * 4 + r);
            if (pend & bit) {
              int row = wg * 16 + q * 4 + r;
              int p = atomicAdd(&qcnt[grp][row], 1);
              if (p < QCAP) {
                qk[grp][row][p] = acc[g][r];
                qm[grp][row][p] = (unsigned short)(m0 + g * 16 + lm);
                pend &= ~bit;
              }
              // else: bit stays set -> retry after drain
            }
          }
        }
      }
      unsigned long long anyovf = __ballot(pend != 0);

      if (handler) {                             // 32 lanes: 16 rows x (L,H)
        int cn = qcnt[grp][hrow];                // same for both pair lanes
        if (cn > QCAP) cn = QCAP;
        for (int p0 = 0; p0 < cn; p0 += 4) {
          float4 kv4 = *(const float4*)&qk[grp][hrow][p0];   // pair-broadcast
          ushort4 mv4 = *(const ushort4*)&qm[grp][hrow][p0];
          float kva[4] = {kv4.x, kv4.y, kv4.z, kv4.w};
          unsigned short mva[4] = {mv4.x, mv4.y, mv4.z, mv4.w};
#pragma unroll
          for (int j = 0; j < 4; j++) {
            bool valid = (p0 + j < cn);
            float kv = kva[j];
            int ki = (int)mva[j];
            // L decides what flows to H: its evicted max, or kv itself
            bool lins = kv < hk[Kh - 1];
            float pv = lins ? hk[Kh - 1] : kv;
            int pi = lins ? hix[Kh - 1] : ki;
            float rv = __shfl_xor(pv, 1);
            int ri = __shfl_xor(pi, 1);
            float mval = isL ? kv : rv;
            int midx = isL ? ki : ri;
            if (valid && mval < hk[Kh - 1]) {    // both roles: same 10-insert
              bool cm[Kh];
#pragma unroll
              for (int kk = 0; kk < Kh; kk++) cm[kk] = mval < hk[kk];
#pragma unroll
              for (int kk = Kh - 1; kk >= 1; kk--) {
                hk[kk]  = cm[kk] ? (cm[kk - 1] ? hk[kk - 1]  : mval) : hk[kk];
                hix[kk] = cm[kk] ? (cm[kk - 1] ? hix[kk - 1] : midx) : hix[kk];
              }
              if (cm[0]) { hk[0] = mval; hix[0] = midx; }
            }
          }
        }
        if (cn && !isL) { qcnt[grp][hrow] = 0; thrS[grp][hrow] = hk[Kh - 1]; }
      }
      if (!anyovf) break;
      // refilter surviving bits against the tightened thresholds
      if (pend) {
        float tl[4];
#pragma unroll
        for (int r = 0; r < 4; r++) tl[r] = thrS[grp][wg * 16 + q * 4 + r];
#pragma unroll
        for (int g = 0; g < 4; g++)
#pragma unroll
          for (int r = 0; r < 4; r++) {
            unsigned bit = 1u << (g * 4 + r);
            if ((pend & bit) && acc[g][r] >= tl[r]) pend &= ~bit;
          }
      }
    }
  }

  // -------- merge: group 1 publishes its rank-sorted 20-list per row
  if (grp == 1 && handler) {
    int base = isL ? 0 : Kh;
#pragma unroll
    for (int kk = 0; kk < Kh; kk++) {
      qk[1][hrow][base + kk] = hk[kk];
      qm[1][hrow][base + kk] = (unsigned short)hix[kk];
    }
  }
  __syncthreads();
  if (grp == 0 && handler) {
    // feed group 1's 20 candidates (ascending key order) through the same
    // pair-insert machinery; group-1 m-indices are all >= 2048 > any
    // group-0 index, so strict '<' keeps sequential-scan tie semantics
    for (int p0 = 0; p0 < Kk; p0 += 4) {
      float4 kv4 = *(const float4*)&qk[1][hrow][p0];
      ushort4 mv4 = *(const ushort4*)&qm[1][hrow][p0];
      float kva[4] = {kv4.x, kv4.y, kv4.z, kv4.w};
      unsigned short mva[4] = {mv4.x, mv4.y, mv4.z, mv4.w};
#pragma unroll
      for (int j = 0; j < 4; j++) {
        float kv = kva[j];
        int ki = (int)mva[j];
        bool lins = kv < hk[Kh - 1];
        float pv = lins ? hk[Kh - 1] : kv;
        int pi = lins ? hix[Kh - 1] : ki;
        float rv = __shfl_xor(pv, 1);
        int ri = __shfl_xor(pi, 1);
        float mval = isL ? kv : rv;
        int midx = isL ? ki : ri;
        if (mval < hk[Kh - 1]) {
          bool cm[Kh];
#pragma unroll
          for (int kk = 0; kk < Kh; kk++) cm[kk] = mval < hk[kk];
#pragma unroll
          for (int kk = Kh - 1; kk >= 1; kk--) {
            hk[kk]  = cm[kk] ? (cm[kk - 1] ? hk[kk - 1]  : mval) : hk[kk];
            hix[kk] = cm[kk] ? (cm[kk - 1] ? hix[kk - 1] : midx) : hix[kk];
          }
          if (cm[0]) { hk[0] = mval; hix[0] = midx; }
        }
      }
    }
    // final write: L lane writes ranks 0-9, H lane ranks 10-19
    size_t obase = ((size_t)b * Nn + n0 + hrow) * Kk + (isL ? 0 : Kh);
#pragma unroll
    for (int kk = 0; kk < Kh; kk++) idxout[obase + kk] = hix[kk];
  }
}

// ---------------------------------------------------------------- k_stats
__global__ __launch_bounds__(256) void k_stats(const float* __restrict__ y1,
                                               const float* __restrict__ z,
                                               const int* __restrict__ idxp,
                                               float* __restrict__ parts) {
  __shared__ float rs[4][64];
  __shared__ float rq[4][64];
  int tid = threadIdx.x;
  int o = tid & 63, g = tid >> 6;
  int b = blockIdx.x & 7;                       // XCD swizzle
  int n0 = (blockIdx.x >> 3) << 6;
  const float* y1b = y1 + (size_t)b * Nn * 64;
  float s = 0.f, ss = 0.f;
  for (int t = 0; t < 16; t++) {
    int n = n0 + g + t * 4;
    size_t base = (size_t)b * Nn + n;
    float zv = z[base * 64 + o];
    const int* ip = idxp + base * Kk;
#pragma unroll
    for (int k = 0; k < Kk; k++) {
      int j = ip[k];
      float hv = y1b[(size_t)j * 64 + o] + zv;
      s += hv;
      ss = fmaf(hv, hv, ss);
    }
  }
  rs[g][o] = s;
  rq[g][o] = ss;
  __syncthreads();
  if (tid < 64) {
    parts[(size_t)blockIdx.x * 128 + tid] = rs[0][tid] + rs[1][tid] + rs[2][tid] + rs[3][tid];
    parts[(size_t)blockIdx.x * 128 + 64 + tid] = rq[0][tid] + rq[1][tid] + rq[2][tid] + rq[3][tid];
  }
}

// ---------------------------------------------------------------- k_reduce
__global__ __launch_bounds__(128) void k_reduce(const float* __restrict__ parts,
                                                float* __restrict__ stats) {
  int tid = threadIdx.x;                         // [0,128)
  float s = 0.f;
  for (int i = 0; i < 512; i += 4) {
    s += parts[(size_t)i * 128 + tid] + parts[(size_t)(i + 1) * 128 + tid] +
         parts[(size_t)(i + 2) * 128 + tid] + parts[(size_t)(i + 3) * 128 + tid];
  }
  stats[tid] = s;
}

// ---------------------------------------------------------------- k_out
__global__ __launch_bounds__(256) void k_out(const float* __restrict__ y1,
                                             const float* __restrict__ z,
                                             const int* __restrict__ idxp,
                                             const float* __restrict__ stats,
                                             const float* __restrict__ gamma,
                                             const float* __restrict__ beta,
                                             float* __restrict__ out) {
  __shared__ float T[64][65];
  int tid = threadIdx.x;
  int lane = tid & 63;
  int w = tid >> 6;
  int b = blockIdx.x & 7;                       // XCD swizzle
  int n0 = (blockIdx.x >> 3) << 6;
  int o = lane;
  const float inv = 1.0f / (float)NTOT;
  float mean = stats[o] * inv;
  float var = fmaf(-mean, mean, stats[64 + o] * inv);
  float sc = gamma[o] * rsqrtf(var + 1e-5f);
  float bi = fmaf(-mean, sc, beta[o]);
  const float* y1b = y1 + (size_t)b * Nn * 64;
  for (int t = 0; t < 16; t++) {
    int nl = w + t * 4;
    size_t base = (size_t)b * Nn + n0 + nl;
    float zv = z[base * 64 + o];
    const int* ip = idxp + base * Kk;
    float mv = -INFINITY;
#pragma unroll
    for (int k = 0; k < Kk; k++) {
      int j = ip[k];
      float hv = y1b[(size_t)j * 64 + o] + zv;
      float hn = fmaf(hv, sc, bi);
      float a = (hn >= 0.f) ? hn : 0.2f * hn;
      mv = fmaxf(mv, a);
    }
    T[o][nl] = mv;
  }
  __syncthreads();
  for (int t = 0; t < 16; t++) {
    int oo = w * 16 + t;
    out[((size_t)b * Oo + oo) * Nn + n0 + lane] = T[oo][lane];
  }
}

// ---------------------------------------------------------------- launch
extern "C" void kernel_launch(void* const* d_in, const int* in_sizes, int n_in,
                              void* d_out, int out_size, void* d_ws, size_t ws_size,
                              hipStream_t stream) {
  const float* x = (const float*)d_in[0];
  const float* W = (const float*)d_in[1];
  const float* gamma = (const float*)d_in[2];
  const float* beta = (const float*)d_in[3];
  // d_in[4] is k (=20), baked in as Kk.

  // workspace layout (bytes):
  //   xs3  : [0,       12582912)  bf16 interleaved [b][n][3*64]  (dead after
  //                                k_knn; y1 overlays [0,8M), z [8M,16M))
  //   y1   : [0,        8388608)  B*N*O fp32  (k_y1z, after k_knn)
  //   z    : [8388608, 16777216)  B*N*O fp32  (k_y1z, after k_knn)
  //   sq   : [16777216,16908288)  B*N fp32
  //   stats: [16908288,16908800)  128 fp32
  //   idx20: [16908800,19530240)  B*N*K int32
  //   parts: [19530240,19792384)  512*128 fp32
  char* ws = (char*)d_ws;
  unsigned short* xs3 = (unsigned short*)ws;
  float* y1 = (float*)ws;
  float* z = (float*)(ws + 8388608);
  float* sq = (float*)(ws + 16777216);
  float* stats = (float*)(ws + 16908288);
  int* idx = (int*)(ws + 16908800);
  float* parts = (float*)(ws + 19530240);
  float* out = (float*)d_out;

  k_split<<<Bn * (Nn / 64), 256, 0, stream>>>(x, xs3, sq);
  k_knn<<<Bn * (Nn / 64), 512, 0, stream>>>(xs3, sq, idx);
  k_y1z<<<Bn * (Nn / 64), 256, 0, stream>>>(x, W, y1, z);
  k_stats<<<Bn * (Nn / 64), 256, 0, stream>>>(y1, z, idx, parts);
  k_reduce<<<1, 128, 0, stream>>>(parts, stats);
  k_out<<<Bn * (Nn / 64), 256, 0, stream>>>(y1, z, idx, stats, gamma, beta, out);
}

// Round 3
// 369.817 us; speedup vs baseline: 1.2714x; 1.0391x over previous
//
#include <hip/hip_runtime.h>
#include <math.h>

// Problem constants (setup_inputs): B=8, C=64, N=4096, O=64, K=20
#define Bn 8
#define Cc 64
#define Nn 4096
#define Oo 64
#define Kk 20
#define Kh 10                // half-list size (rank-split pair handlers)
#define QCAP 16              // per-row candidate queue capacity per tile
#define NTOT (Bn*Nn*Kk)      // 655360 elements per BN channel

typedef __attribute__((ext_vector_type(8))) short short8;
typedef __attribute__((ext_vector_type(4))) float f32x4;

__device__ __forceinline__ unsigned bf16_rn(float v) {
  unsigned u = __float_as_uint(v);
  return (u + 0x7FFFu + ((u >> 16) & 1)) >> 16;     // RN-even
}

// lane-pair swap (lane 2k <-> 2k+1) via DPP quad_perm [1,0,3,2]:
// 1-cycle VALU, no lgkm round-trip (vs ds_bpermute from __shfl_xor)
__device__ __forceinline__ float pair_swap_f(float v) {
  return __int_as_float(__builtin_amdgcn_mov_dpp(__float_as_int(v), 0xB1, 0xF, 0xF, true));
}
__device__ __forceinline__ int pair_swap_i(int v) {
  return __builtin_amdgcn_mov_dpp(v, 0xB1, 0xF, 0xF, true);
}

// ---------------------------------------------------------------- k_split
// x fp32 [b][c][n] -> INTERLEAVED 3-term bf16 split xs3[b][n][{h|m|l}*64+c]
// (192 shorts/row), plus sq[b][n].
//   h = RN(x); m = RN(x-h); l = RN(x-h-m)   (x-h, x-h-m exact in fp32)
__global__ __launch_bounds__(256) void k_split(const float* __restrict__ x,
                                               unsigned short* __restrict__ xs3,
                                               float* __restrict__ sqv) {
  __shared__ float xs[64][68];                  // [c][n], float4-friendly pad
  int tid = threadIdx.x;
  int b = blockIdx.x & 7;
  int n0 = (blockIdx.x >> 3) << 6;
  for (int i = 0; i < 4; i++) {
    int c = i * 16 + (tid >> 4);
    int n = (tid & 15) * 4;
    float4 v = *(const float4*)&x[((size_t)b * Cc + c) * Nn + n0 + n];
    *(float4*)&xs[c][n] = v;
  }
  __syncthreads();
  for (int i = 0; i < 4; i++) {
    int n = i * 16 + (tid >> 4);
    int c = (tid & 15) * 4;
    ushort4 h4, m4, l4;
    unsigned short* hp = (unsigned short*)&h4;
    unsigned short* mp = (unsigned short*)&m4;
    unsigned short* lp = (unsigned short*)&l4;
#pragma unroll
    for (int j = 0; j < 4; j++) {
      float v = xs[c + j][n];
      unsigned hb = bf16_rn(v);
      float hf = __uint_as_float(hb << 16);
      float r1 = v - hf;                                     // exact
      unsigned mb = bf16_rn(r1);
      float mf = __uint_as_float(mb << 16);
      float r2 = r1 - mf;                                    // exact
      unsigned lb = bf16_rn(r2);
      hp[j] = (unsigned short)hb;
      mp[j] = (unsigned short)mb;
      lp[j] = (unsigned short)lb;
    }
    size_t o = ((size_t)(b << 12) + n0 + n) * 192 + c;
    *(ushort4*)&xs3[o] = h4;
    *(ushort4*)&xs3[o + 64] = m4;
    *(ushort4*)&xs3[o + 128] = l4;
  }
  if (tid < 64) {
    float s = 0.f;
#pragma unroll
    for (int c = 0; c < 64; c++) { float v = xs[c][tid]; s = fmaf(v, v, s); }
    sqv[b * Nn + n0 + tid] = s;
  }
}

// ---------------------------------------------------------------- k_y1z
__global__ __launch_bounds__(256) void k_y1z(const float* __restrict__ x,
                                             const float* __restrict__ Wm,
                                             float* __restrict__ y1,
                                             float* __restrict__ z) {
  __shared__ float xs[64][68];                  // [c][n]
  __shared__ float Wl[64][129];
  int tid = threadIdx.x;
  int b = blockIdx.x & 7;
  int n0 = (blockIdx.x >> 3) << 6;
  for (int i = tid; i < 64 * 128; i += 256) Wl[i >> 7][i & 127] = Wm[i];
  for (int i = 0; i < 4; i++) {
    int c = i * 16 + (tid >> 4);
    int n = (tid & 15) * 4;
    float4 v = *(const float4*)&x[((size_t)b * Cc + c) * Nn + n0 + n];
    *(float4*)&xs[c][n] = v;
  }
  __syncthreads();
  int o = tid & 63, ng = tid >> 6;              // ng == wave id -> nb uniform
  for (int p = 0; p < 4; p++) {
    int nb = p * 16 + ng * 4;
    float a1[4] = {0.f, 0.f, 0.f, 0.f};
    float a2[4] = {0.f, 0.f, 0.f, 0.f};
#pragma unroll 8
    for (int c = 0; c < 64; c++) {
      float4 xv = *(const float4*)&xs[c][nb];   // wave-broadcast
      float w1v = Wl[o][c], w2v = Wl[o][64 + c];
      float xa[4] = {xv.x, xv.y, xv.z, xv.w};
#pragma unroll
      for (int j = 0; j < 4; j++) {
        a1[j] = fmaf(xa[j], w1v, a1[j]);
        a2[j] = fmaf(xa[j], w2v, a2[j]);
      }
    }
#pragma unroll
    for (int j = 0; j < 4; j++) {
      size_t off = ((size_t)b * Nn + n0 + nb + j) * 64 + o;
      y1[off] = a1[j];
      z[off] = a2[j] - a1[j];
    }
  }
}

// ---------------------------------------------------------------- k_knn (v14)
// v13 + three drain-cost cuts (VALU was 139us of 254us; drain machinery is
// ~75% of it):
//  1. SAFE ONE-WAY THRESHOLD SHARING: group 1 filters with min(thr1, thr0).
//     Safe: a g1 candidate with key >= current thr0 is beaten by 20
//     lower-index g0 elements (all g0 indices < all g1 indices; strict '<'
//     insert = ties to lower index). g0 must NOT use thr1 (unsafe direction).
//     Cuts g1 insert work ~40%.
//  2. Drain body unroll 4->2: converged-phase drains have cn in {1,2} on the
//     busiest row; the 4x body issued ~240 instr regardless. Flood unchanged.
//  3. DPP pair-swap (quad_perm [1,0,3,2]) replaces __shfl_xor(.,1): removes
//     2 ds_bpermute lgkm round-trips from every insert's serial chain.
__global__ __launch_bounds__(512, 4) void k_knn(const unsigned short* __restrict__ xs3,
                                                const float* __restrict__ sqv,
                                                int* __restrict__ idxout) {
  __shared__ alignas(16) short Bs[2][3][64][72]; // [grp][h/m/l][m][c], padded
  __shared__ float thrS[2][64];
  __shared__ float sqs[2][64];
  __shared__ alignas(16) float qk[2][64][20];    // 80B rows, float4-aligned
  __shared__ alignas(16) unsigned short qm[2][64][24]; // 48B rows, ushort4-aligned
  __shared__ int qcnt[2][64];

  const int tid = threadIdx.x;
  const int lane = tid & 63;
  const int w = tid >> 6;                        // 0..7
  const int grp = w >> 2;                        // m-range group
  const int wg = w & 3;                          // wave within group
  const int tig = tid & 255;                     // thread within group
  const int b = blockIdx.x & 7;                  // XCD swizzle: batch per XCD
  const int n0 = (blockIdx.x >> 3) << 6;         // 64 row-blocks x 64 rows
  const int lm = lane & 15;                      // candidate col / A row slot
  const int q = lane >> 4;                       // quad: C row = q*4+r
  const bool handler = (lane < 32);
  const int hrow = wg * 16 + (lane >> 1);        // row for this handler pair
  const bool isL = (lane & 1) == 0;              // L = ranks 0-9, H = 10-19

  // handler half-list: sorted ascending 10-list in registers
  float hk[Kh];
  int hix[Kh];
#pragma unroll
  for (int kk = 0; kk < Kh; kk++) { hk[kk] = INFINITY; hix[kk] = 0; }

  if (handler && !isL) { thrS[grp][hrow] = INFINITY; qcnt[grp][hrow] = 0; }

  // A fragments: wave owns 16 DISTINCT rows n0 + wg*16 + lm (one wave per
  // group covers each row-set; the two waves scan disjoint m-halves)
  const size_t arow = ((size_t)(b << 12) + n0 + wg * 16 + lm) * 192;
  short8 ah0 = *(const short8*)&xs3[arow + q * 8];
  short8 ah1 = *(const short8*)&xs3[arow + 32 + q * 8];
  short8 am0 = *(const short8*)&xs3[arow + 64 + q * 8];
  short8 am1 = *(const short8*)&xs3[arow + 96 + q * 8];
  short8 al0 = *(const short8*)&xs3[arow + 128 + q * 8];
  short8 al1 = *(const short8*)&xs3[arow + 160 + q * 8];

  // staging: per-thread source pointer (incremented) + 6 fixed LDS dests
  const unsigned short* gp = xs3 + ((size_t)(b << 12) + grp * 2048) * 192 + tig * 8;
  short* ld[6];
#pragma unroll
  for (int i = 0; i < 6; i++) {
    int f = i * 256 + tig;                       // chunk id in [0,1536)
    int r = f / 24;                              // B row
    int rem = f - r * 24;
    int layer = rem >> 3;
    int qq = rem & 7;
    ld[i] = &Bs[grp][layer][r][qq * 8];
  }

  f32x4 acc[4];

  for (int t = 0; t < 32; t++) {
    const int m0 = grp * 2048 + t * 64;
    __syncthreads();                              // all waves done reading Bs
#pragma unroll
    for (int i = 0; i < 6; i++) {
      short8 v = *(const short8*)(gp + i * 2048);
      *(short8*)ld[i] = v;
    }
    gp += 12288;                                  // next 64 rows
    if (tig < 16) ((float4*)sqs[grp])[tig] = ((const float4*)(sqv + b * Nn + m0))[tig];
    __syncthreads();                              // staging visible

#pragma unroll
    for (int g = 0; g < 4; g++) {
      const int mr = g * 16 + lm;
      short8 bh0 = *(const short8*)&Bs[grp][0][mr][q * 8];
      short8 bh1 = *(const short8*)&Bs[grp][0][mr][32 + q * 8];
      short8 bm0 = *(const short8*)&Bs[grp][1][mr][q * 8];
      short8 bm1 = *(const short8*)&Bs[grp][1][mr][32 + q * 8];
      short8 bl0 = *(const short8*)&Bs[grp][2][mr][q * 8];
      short8 bl1 = *(const short8*)&Bs[grp][2][mr][32 + q * 8];
      f32x4 a = (f32x4){0.f, 0.f, 0.f, 0.f};
      a = __builtin_amdgcn_mfma_f32_16x16x32_bf16(am0, bm0, a, 0, 0, 0);  // mm
      a = __builtin_amdgcn_mfma_f32_16x16x32_bf16(am1, bm1, a, 0, 0, 0);
      a = __builtin_amdgcn_mfma_f32_16x16x32_bf16(ah0, bl0, a, 0, 0, 0);  // hl
      a = __builtin_amdgcn_mfma_f32_16x16x32_bf16(ah1, bl1, a, 0, 0, 0);
      a = __builtin_amdgcn_mfma_f32_16x16x32_bf16(al0, bh0, a, 0, 0, 0);  // lh
      a = __builtin_amdgcn_mfma_f32_16x16x32_bf16(al1, bh1, a, 0, 0, 0);
      a = __builtin_amdgcn_mfma_f32_16x16x32_bf16(ah0, bm0, a, 0, 0, 0);  // hm
      a = __builtin_amdgcn_mfma_f32_16x16x32_bf16(ah1, bm1, a, 0, 0, 0);
      a = __builtin_amdgcn_mfma_f32_16x16x32_bf16(am0, bh0, a, 0, 0, 0);  // mh
      a = __builtin_amdgcn_mfma_f32_16x16x32_bf16(am1, bh1, a, 0, 0, 0);
      a = __builtin_amdgcn_mfma_f32_16x16x32_bf16(ah0, bh0, a, 0, 0, 0);  // hh
      a = __builtin_amdgcn_mfma_f32_16x16x32_bf16(ah1, bh1, a, 0, 0, 0);
      acc[g] = a;
    }

    // keys = sq[m] - 2*dot; all 64 lanes hold unique (row=q*4+r, col)
    unsigned pend = 0;
    {
      float tl[4];
#pragma unroll
      for (int r = 0; r < 4; r++) tl[r] = thrS[grp][wg * 16 + q * 4 + r];
      if (grp) {                                  // safe direction only
#pragma unroll
        for (int r = 0; r < 4; r++) tl[r] = fminf(tl[r], thrS[0][wg * 16 + q * 4 + r]);
      }
#pragma unroll
      for (int g = 0; g < 4; g++) {
        float sv = sqs[grp][g * 16 + lm];
#pragma unroll
        for (int r = 0; r < 4; r++) {
          float key = fmaf(-2.f, acc[g][r], sv);
          acc[g][r] = key;
          if (key < tl[r]) pend |= 1u << (g * 4 + r);
        }
      }
    }

    // wave-private push / drain: NO __syncthreads (DS in-order per wave;
    // each wave pushes/drains only its own 16 rows within its group)
    for (;;) {
      if (pend) {
#pragma unroll
        for (int g = 0; g < 4; g++) {
#pragma unroll
          for (int r = 0; r < 4; r++) {
            unsigned bit = 1u << (g * 4 + r);
            if (pend & bit) {
              int row = wg * 16 + q * 4 + r;
              int p = atomicAdd(&qcnt[grp][row], 1);
              if (p < QCAP) {
                qk[grp][row][p] = acc[g][r];
                qm[grp][row][p] = (unsigned short)(m0 + g * 16 + lm);
                pend &= ~bit;
              }
              // else: bit stays set -> retry after drain
            }
          }
        }
      }
      unsigned long long anyovf = __ballot(pend != 0);

      if (handler) {                             // 32 lanes: 16 rows x (L,H)
        int cn = qcnt[grp][hrow];                // same for both pair lanes
        if (cn > QCAP) cn = QCAP;
        for (int p0 = 0; p0 < cn; p0 += 2) {
          float2 kv2 = *(const float2*)&qk[grp][hrow][p0];   // pair-broadcast
          ushort2 mv2 = *(const ushort2*)&qm[grp][hrow][p0];
          float kva[2] = {kv2.x, kv2.y};
          unsigned short mva[2] = {mv2.x, mv2.y};
#pragma unroll
          for (int j = 0; j < 2; j++) {
            bool valid = (p0 + j < cn);
            float kv = kva[j];
            int ki = (int)mva[j];
            // L decides what flows to H: its evicted max, or kv itself
            bool lins = kv < hk[Kh - 1];
            float pv = lins ? hk[Kh - 1] : kv;
            int pi = lins ? hix[Kh - 1] : ki;
            float rv = pair_swap_f(pv);
            int ri = pair_swap_i(pi);
            float mval = isL ? kv : rv;
            int midx = isL ? ki : ri;
            if (valid && mval < hk[Kh - 1]) {    // both roles: same 10-insert
              bool cm[Kh];
#pragma unroll
              for (int kk = 0; kk < Kh; kk++) cm[kk] = mval < hk[kk];
#pragma unroll
              for (int kk = Kh - 1; kk >= 1; kk--) {
                hk[kk]  = cm[kk] ? (cm[kk - 1] ? hk[kk - 1]  : mval) : hk[kk];
                hix[kk] = cm[kk] ? (cm[kk - 1] ? hix[kk - 1] : midx) : hix[kk];
              }
              if (cm[0]) { hk[0] = mval; hix[0] = midx; }
            }
          }
        }
        if (cn && !isL) { qcnt[grp][hrow] = 0; thrS[grp][hrow] = hk[Kh - 1]; }
      }
      if (!anyovf) break;
      // refilter surviving bits against the tightened thresholds
      if (pend) {
        float tl[4];
#pragma unroll
        for (int r = 0; r < 4; r++) tl[r] = thrS[grp][wg * 16 + q * 4 + r];
        if (grp) {
#pragma unroll
          for (int r = 0; r < 4; r++) tl[r] = fminf(tl[r], thrS[0][wg * 16 + q * 4 + r]);
        }
#pragma unroll
        for (int g = 0; g < 4; g++)
#pragma unroll
          for (int r = 0; r < 4; r++) {
            unsigned bit = 1u << (g * 4 + r);
            if ((pend & bit) && acc[g][r] >= tl[r]) pend &= ~bit;
          }
      }
    }
  }

  // -------- merge: group 1 publishes its rank-sorted 20-list per row
  if (grp == 1 && handler) {
    int base = isL ? 0 : Kh;
#pragma unroll
    for (int kk = 0; kk < Kh; kk++) {
      qk[1][hrow][base + kk] = hk[kk];
      qm[1][hrow][base + kk] = (unsigned short)hix[kk];
    }
  }
  __syncthreads();
  if (grp == 0 && handler) {
    // feed group 1's 20 candidates (ascending key order) through the same
    // pair-insert machinery; group-1 m-indices are all >= 2048 > any
    // group-0 index, so strict '<' keeps sequential-scan tie semantics
    for (int p0 = 0; p0 < Kk; p0 += 4) {
      float4 kv4 = *(const float4*)&qk[1][hrow][p0];
      ushort4 mv4 = *(const ushort4*)&qm[1][hrow][p0];
      float kva[4] = {kv4.x, kv4.y, kv4.z, kv4.w};
      unsigned short mva[4] = {mv4.x, mv4.y, mv4.z, mv4.w};
#pragma unroll
      for (int j = 0; j < 4; j++) {
        float kv = kva[j];
        int ki = (int)mva[j];
        bool lins = kv < hk[Kh - 1];
        float pv = lins ? hk[Kh - 1] : kv;
        int pi = lins ? hix[Kh - 1] : ki;
        float rv = pair_swap_f(pv);
        int ri = pair_swap_i(pi);
        float mval = isL ? kv : rv;
        int midx = isL ? ki : ri;
        if (mval < hk[Kh - 1]) {
          bool cm[Kh];
#pragma unroll
          for (int kk = 0; kk < Kh; kk++) cm[kk] = mval < hk[kk];
#pragma unroll
          for (int kk = Kh - 1; kk >= 1; kk--) {
            hk[kk]  = cm[kk] ? (cm[kk - 1] ? hk[kk - 1]  : mval) : hk[kk];
            hix[kk] = cm[kk] ? (cm[kk - 1] ? hix[kk - 1] : midx) : hix[kk];
          }
          if (cm[0]) { hk[0] = mval; hix[0] = midx; }
        }
      }
    }
    // final write: L lane writes ranks 0-9, H lane ranks 10-19
    size_t obase = ((size_t)b * Nn + n0 + hrow) * Kk + (isL ? 0 : Kh);
#pragma unroll
    for (int kk = 0; kk < Kh; kk++) idxout[obase + kk] = hix[kk];
  }
}

// ---------------------------------------------------------------- k_stats
__global__ __launch_bounds__(256) void k_stats(const float* __restrict__ y1,
                                               const float* __restrict__ z,
                                               const int* __restrict__ idxp,
                                               float* __restrict__ parts) {
  __shared__ float rs[4][64];
  __shared__ float rq[4][64];
  int tid = threadIdx.x;
  int o = tid & 63, g = tid >> 6;
  int b = blockIdx.x & 7;                       // XCD swizzle
  int n0 = (blockIdx.x >> 3) << 6;
  const float* y1b = y1 + (size_t)b * Nn * 64;
  float s = 0.f, ss = 0.f;
  for (int t = 0; t < 16; t++) {
    int n = n0 + g + t * 4;
    size_t base = (size_t)b * Nn + n;
    float zv = z[base * 64 + o];
    const int* ip = idxp + base * Kk;
#pragma unroll
    for (int k = 0; k < Kk; k++) {
      int j = ip[k];
      float hv = y1b[(size_t)j * 64 + o] + zv;
      s += hv;
      ss = fmaf(hv, hv, ss);
    }
  }
  rs[g][o] = s;
  rq[g][o] = ss;
  __syncthreads();
  if (tid < 64) {
    parts[(size_t)blockIdx.x * 128 + tid] = rs[0][tid] + rs[1][tid] + rs[2][tid] + rs[3][tid];
    parts[(size_t)blockIdx.x * 128 + 64 + tid] = rq[0][tid] + rq[1][tid] + rq[2][tid] + rq[3][tid];
  }
}

// ---------------------------------------------------------------- k_reduce
__global__ __launch_bounds__(128) void k_reduce(const float* __restrict__ parts,
                                                float* __restrict__ stats) {
  int tid = threadIdx.x;                         // [0,128)
  float s = 0.f;
  for (int i = 0; i < 512; i += 4) {
    s += parts[(size_t)i * 128 + tid] + parts[(size_t)(i + 1) * 128 + tid] +
         parts[(size_t)(i + 2) * 128 + tid] + parts[(size_t)(i + 3) * 128 + tid];
  }
  stats[tid] = s;
}

// ---------------------------------------------------------------- k_out
__global__ __launch_bounds__(256) void k_out(const float* __restrict__ y1,
                                             const float* __restrict__ z,
                                             const int* __restrict__ idxp,
                                             const float* __restrict__ stats,
                                             const float* __restrict__ gamma,
                                             const float* __restrict__ beta,
                                             float* __restrict__ out) {
  __shared__ float T[64][65];
  int tid = threadIdx.x;
  int lane = tid & 63;
  int w = tid >> 6;
  int b = blockIdx.x & 7;                       // XCD swizzle
  int n0 = (blockIdx.x >> 3) << 6;
  int o = lane;
  const float inv = 1.0f / (float)NTOT;
  float mean = stats[o] * inv;
  float var = fmaf(-mean, mean, stats[64 + o] * inv);
  float sc = gamma[o] * rsqrtf(var + 1e-5f);
  float bi = fmaf(-mean, sc, beta[o]);
  const float* y1b = y1 + (size_t)b * Nn * 64;
  for (int t = 0; t < 16; t++) {
    int nl = w + t * 4;
    size_t base = (size_t)b * Nn + n0 + nl;
    float zv = z[base * 64 + o];
    const int* ip = idxp + base * Kk;
    float mv = -INFINITY;
#pragma unroll
    for (int k = 0; k < Kk; k++) {
      int j = ip[k];
      float hv = y1b[(size_t)j * 64 + o] + zv;
      float hn = fmaf(hv, sc, bi);
      float a = (hn >= 0.f) ? hn : 0.2f * hn;
      mv = fmaxf(mv, a);
    }
    T[o][nl] = mv;
  }
  __syncthreads();
  for (int t = 0; t < 16; t++) {
    int oo = w * 16 + t;
    out[((size_t)b * Oo + oo) * Nn + n0 + lane] = T[oo][lane];
  }
}

// ---------------------------------------------------------------- launch
extern "C" void kernel_launch(void* const* d_in, const int* in_sizes, int n_in,
                              void* d_out, int out_size, void* d_ws, size_t ws_size,
                              hipStream_t stream) {
  const float* x = (const float*)d_in[0];
  const float* W = (const float*)d_in[1];
  const float* gamma = (const float*)d_in[2];
  const float* beta = (const float*)d_in[3];
  // d_in[4] is k (=20), baked in as Kk.

  // workspace layout (bytes):
  //   xs3  : [0,       12582912)  bf16 interleaved [b][n][3*64]  (dead after
  //                                k_knn; y1 overlays [0,8M), z [8M,16M))
  //   y1   : [0,        8388608)  B*N*O fp32  (k_y1z, after k_knn)
  //   z    : [8388608, 16777216)  B*N*O fp32  (k_y1z, after k_knn)
  //   sq   : [16777216,16908288)  B*N fp32
  //   stats: [16908288,16908800)  128 fp32
  //   idx20: [16908800,19530240)  B*N*K int32
  //   parts: [19530240,19792384)  512*128 fp32
  char* ws = (char*)d_ws;
  unsigned short* xs3 = (unsigned short*)ws;
  float* y1 = (float*)ws;
  float* z = (float*)(ws + 8388608);
  float* sq = (float*)(ws + 16777216);
  float* stats = (float*)(ws + 16908288);
  int* idx = (int*)(ws + 16908800);
  float* parts = (float*)(ws + 19530240);
  float* out = (float*)d_out;

  k_split<<<Bn * (Nn / 64), 256, 0, stream>>>(x, xs3, sq);
  k_knn<<<Bn * (Nn / 64), 512, 0, stream>>>(xs3, sq, idx);
  k_y1z<<<Bn * (Nn / 64), 256, 0, stream>>>(x, W, y1, z);
  k_stats<<<Bn * (Nn / 64), 256, 0, stream>>>(y1, z, idx, parts);
  k_reduce<<<1, 128, 0, stream>>>(parts, stats);
  k_out<<<Bn * (Nn / 64), 256, 0, stream>>>(y1, z, idx, stats, gamma, beta, out);
}